// Round 5
// baseline (318.424 us; speedup 1.0000x reference)
//
#include <hip/hip_runtime.h>
#include <stdint.h>

#define B_ 1024
#define D_ 784
#define H_ 1024
#define BH_ (B_ * H_)
#define LOG2E 1.4426950408889634f

// Segments: {0,200,392,592,784}; G ranges: first 3 spans.
// nade_main v3: 1 wave = 1 row, 16 h/lane; the two 8-trees (h-halves A/B) are
// FUSED element-wise into float2 ext-vectors so the backend can emit packed
// dual-issue FP32 (v_pk_fma_f32/v_pk_mul_f32/v_pk_add_f32) for the k-loop and
// the whole combine tree. exp2/min/shifts stay scalar (no packed trans).
// R4 showed busy-cyc/elem identical across structures -> inner arithmetic is
// the whole cost; pk halves its issue slots.
// __launch_bounds__(256,4): 128-VGPR cap keeps 16 waves/CU; WRITE_SIZE is the
// spill tripwire (R2 lesson).
// VWb: per (step i, hb) 1KB image of 512 ushorts: [0,256) V bf16, [256,512) W*log2e bf16.
// ws: VWb [788][4][512] ushort 3.23 MB | G [3][B][H] fp32 12.6 MB

typedef float v2f __attribute__((ext_vector_type(2)));

__device__ __forceinline__ unsigned short bf16_rne(float x) {
    unsigned b = __float_as_uint(x);
    return (unsigned short)((b + 0x7FFFu + ((b >> 16) & 1u)) >> 16);
}

__device__ __forceinline__ int seg_bound(int s) {
    const int b[5] = {0, 200, 392, 592, 784};
    return b[s];
}

// ---------- fat prep (unchanged, verified) ----------
__global__ __launch_bounds__(256) void prep(const float* __restrict__ V,
                                            const float* __restrict__ W,
                                            const float* __restrict__ px,
                                            unsigned short* __restrict__ VWb,
                                            float* __restrict__ G) {
    __shared__ float smem[1056];
    const int t = threadIdx.x;

    if (blockIdx.x < 800) {
        int i0 = (blockIdx.x % 25) * 32;
        int h0 = (blockIdx.x / 25) * 32;
        int tx = t & 31, ty = t >> 5;   // 32 x 8
        int hb = h0 >> 8, hr = h0 & 255;
#pragma unroll
        for (int j = 0; j < 4; ++j) {
            int i = i0 + ty + j * 8;
            if (i < D_)
                VWb[((size_t)i * 4 + hb) * 512 + hr + tx] = bf16_rne(V[(size_t)i * H_ + h0 + tx]);
        }
#pragma unroll
        for (int j = 0; j < 4; ++j) {
            int h = h0 + ty + j * 8;
            int i = i0 + tx;
            float v = 0.f;
            if (i < D_) v = W[(size_t)h * D_ + i] * LOG2E;
            smem[(ty + j * 8) * 33 + tx] = v;
        }
        __syncthreads();
#pragma unroll
        for (int j = 0; j < 4; ++j) {
            int i = i0 + ty + j * 8;
            if (i < D_)
                VWb[((size_t)i * 4 + hb) * 512 + 256 + hr + tx] = bf16_rne(smem[tx * 33 + ty + j * 8]);
        }
    } else {
        float* xs = smem;          // [8][64]
        float* ws = smem + 512;    // [8][64]
        int idx = blockIdx.x - 800;
        int r   = idx >> 8;                       // 0..2
        int b0  = (idx & 15) * 64;
        int h0  = ((idx >> 4) & 15) * 64;
        int j0s = seg_bound(r), j1s = seg_bound(r + 1);

        const int tb = t >> 4, th = t & 15;       // 16x16, each 4b x 4h
        float acc[4][4];
#pragma unroll
        for (int bi = 0; bi < 4; ++bi)
#pragma unroll
            for (int hh = 0; hh < 4; ++hh) acc[bi][hh] = 0.f;

        const int xb = t >> 3;                    // 0..31
        const int xj = t & 7;                     // 0..7
        const int wh = t >> 1, wj = (t & 1) * 4;  // for t < 128

        for (int j0 = j0s; j0 < j1s; j0 += 8) {   // range lengths all %8 == 0
            float xv0 = px[(size_t)(b0 + xb) * D_ + j0 + xj];
            float xv1 = px[(size_t)(b0 + 32 + xb) * D_ + j0 + xj];
            float4 wv = make_float4(0, 0, 0, 0);
            if (t < 128) wv = *(const float4*)(W + (size_t)(h0 + wh) * D_ + j0 + wj);
            __syncthreads();
            xs[xj * 64 + xb]      = xv0;
            xs[xj * 64 + 32 + xb] = xv1;
            if (t < 128) {
                ws[(wj + 0) * 64 + wh] = wv.x * LOG2E;
                ws[(wj + 1) * 64 + wh] = wv.y * LOG2E;
                ws[(wj + 2) * 64 + wh] = wv.z * LOG2E;
                ws[(wj + 3) * 64 + wh] = wv.w * LOG2E;
            }
            __syncthreads();
#pragma unroll
            for (int jj = 0; jj < 8; ++jj) {
                float4 xq = *(float4*)&xs[jj * 64 + tb * 4];
                float4 wq = *(float4*)&ws[jj * 64 + th * 4];
                float xa[4] = {xq.x, xq.y, xq.z, xq.w};
                float wa[4] = {wq.x, wq.y, wq.z, wq.w};
#pragma unroll
                for (int bi = 0; bi < 4; ++bi)
#pragma unroll
                    for (int hh = 0; hh < 4; ++hh)
                        acc[bi][hh] = fmaf(xa[bi], wa[hh], acc[bi][hh]);
            }
        }
        float* dst = G + (size_t)r * BH_;
#pragma unroll
        for (int bi = 0; bi < 4; ++bi) {
            float4 o = make_float4(acc[bi][0], acc[bi][1], acc[bi][2], acc[bi][3]);
            *(float4*)(dst + (size_t)(b0 + tb * 4 + bi) * H_ + h0 + th * 4) = o;
        }
    }
}

// ---------- DPP reduce: full 64-lane sum into lane 63 ----------
template <int CTRL>
__device__ __forceinline__ float dpp_add(float p) {
    int s = __builtin_amdgcn_update_dpp(0, __float_as_int(p), CTRL, 0xf, 0xf, true);
    return p + __int_as_float(s);
}
__device__ __forceinline__ float reduce64(float p) {
    p = dpp_add<0x111>(p);   // row_shr:1
    p = dpp_add<0x112>(p);   // row_shr:2
    p = dpp_add<0x114>(p);   // row_shr:4
    p = dpp_add<0x118>(p);   // row_shr:8
    p = dpp_add<0x142>(p);   // row_bcast:15 -> lane31 = sum(0..31), lane63 = sum(32..63)
    p = dpp_add<0x143>(p);   // row_bcast:31 -> lane63 = sum(0..63)
    return p;
}

// Unpack two uint4 bf16 images (8 elems each) into 8 float2 pairs
// (.x from image A, .y from image B). High halves keep junk mantissa bits.
__device__ __forceinline__ void unpack_pair(const uint4& uA, const uint4& uB, v2f (&o)[8]) {
    o[0].x = __uint_as_float(uA.x << 16); o[0].y = __uint_as_float(uB.x << 16);
    o[1].x = __uint_as_float(uA.x);       o[1].y = __uint_as_float(uB.x);
    o[2].x = __uint_as_float(uA.y << 16); o[2].y = __uint_as_float(uB.y << 16);
    o[3].x = __uint_as_float(uA.y);       o[3].y = __uint_as_float(uB.y);
    o[4].x = __uint_as_float(uA.z << 16); o[4].y = __uint_as_float(uB.z << 16);
    o[5].x = __uint_as_float(uA.z);       o[5].y = __uint_as_float(uB.z);
    o[6].x = __uint_as_float(uA.w << 16); o[6].y = __uint_as_float(uB.w << 16);
    o[7].x = __uint_as_float(uA.w);       o[7].y = __uint_as_float(uB.w);
}

// Fused dual 8-wide rational tree on float2 (component .x = h-half A, .y = h-half B).
// d = prod q, n = sum v_k * prod_{j!=k} q_j per component; clamp 15 keeps d <= 2^120.
// Also performs the packed A rank-1 update.
__device__ __forceinline__ void tree16(v2f (&Aq)[8],
                                       const uint4& uvA, const uint4& uwA,
                                       const uint4& uvB, const uint4& uwB,
                                       float xi, v2f& n, v2f& d) {
    v2f va[8], wa[8];
    unpack_pair(uvA, uvB, va);
    unpack_pair(uwA, uwB, wa);
    const v2f one = {1.f, 1.f};
    v2f xiv; xiv.x = xi; xiv.y = xi;
    v2f q[8];
#pragma unroll
    for (int k = 0; k < 8; ++k) {
        float ex = __builtin_amdgcn_exp2f(fminf(15.f, -Aq[k].x));
        float ey = __builtin_amdgcn_exp2f(fminf(15.f, -Aq[k].y));
        v2f e; e.x = ex; e.y = ey;
        q[k] = one + e;                 // v_pk_add_f32
        Aq[k] = wa[k] * xiv + Aq[k];    // v_pk_fma_f32 (fp-contract)
    }
    v2f a01 = va[0] * q[1] + va[1] * q[0];
    v2f a23 = va[2] * q[3] + va[3] * q[2];
    v2f a45 = va[4] * q[5] + va[5] * q[4];
    v2f a67 = va[6] * q[7] + va[7] * q[6];
    v2f q01 = q[0] * q[1], q23 = q[2] * q[3];
    v2f q45 = q[4] * q[5], q67 = q[6] * q[7];
    v2f n0123 = a01 * q23 + a23 * q01;
    v2f n4567 = a45 * q67 + a67 * q45;
    v2f q0123 = q01 * q23, q4567 = q45 * q67;
    d = q0123 * q4567;
    n = n0123 * q4567 + n4567 * q0123;
}

// ---------- main scan v3: 1 wave = 1 row, 16 h/lane, packed f32 ----------
__global__ __launch_bounds__(256, 4) void nade_main(
    const float* __restrict__ px,            // [B, D]
    const float* __restrict__ c,             // [H]
    const unsigned short* __restrict__ VWb,  // bf16 images
    const float* __restrict__ G,             // [3][B][H] (log2 domain)
    const float* __restrict__ bias,          // [D]
    float* __restrict__ out)                 // [B, D]
{
    const int lane = threadIdx.x & 63;
    const int wid  = threadIdx.x >> 6;
    const int bid  = blockIdx.x;             // 0..1023
    const int s    = bid >> 8;               // 0..3
    const int rb   = bid & 255;              // row-block
    const int row  = rb * 4 + wid;           // this wave's row

    const int i0s = seg_bound(s), i1s = seg_bound(s + 1);

    // lane handles h = lane*8..+7 (component .x) and 512+lane*8..+7 (component .y)
    const int hA = lane * 8;
    const int hB = 512 + hA;

    v2f Aq[8];
    {
        float4 c0 = *(const float4*)(c + hA);
        float4 c1 = *(const float4*)(c + hA + 4);
        float4 c2 = *(const float4*)(c + hB);
        float4 c3 = *(const float4*)(c + hB + 4);
        Aq[0].x = c0.x * LOG2E; Aq[0].y = c2.x * LOG2E;
        Aq[1].x = c0.y * LOG2E; Aq[1].y = c2.y * LOG2E;
        Aq[2].x = c0.z * LOG2E; Aq[2].y = c2.z * LOG2E;
        Aq[3].x = c0.w * LOG2E; Aq[3].y = c2.w * LOG2E;
        Aq[4].x = c1.x * LOG2E; Aq[4].y = c3.x * LOG2E;
        Aq[5].x = c1.y * LOG2E; Aq[5].y = c3.y * LOG2E;
        Aq[6].x = c1.z * LOG2E; Aq[6].y = c3.z * LOG2E;
        Aq[7].x = c1.w * LOG2E; Aq[7].y = c3.w * LOG2E;
        for (int r = 0; r < s; ++r) {
            const float* gp = G + (size_t)r * BH_ + (size_t)row * H_;
            float4 g0 = *(const float4*)(gp + hA);
            float4 g1 = *(const float4*)(gp + hA + 4);
            float4 g2 = *(const float4*)(gp + hB);
            float4 g3 = *(const float4*)(gp + hB + 4);
            Aq[0].x += g0.x; Aq[0].y += g2.x;
            Aq[1].x += g0.y; Aq[1].y += g2.y;
            Aq[2].x += g0.z; Aq[2].y += g2.z;
            Aq[3].x += g0.w; Aq[3].y += g2.w;
            Aq[4].x += g1.x; Aq[4].y += g3.x;
            Aq[5].x += g1.y; Aq[5].y += g3.y;
            Aq[6].x += g1.z; Aq[6].y += g3.z;
            Aq[7].x += g1.w; Aq[7].y += g3.w;
        }
    }

    const float* xp = px + (size_t)row * D_;
    // uint4 view of image i: 256 uint4 per image; lane's slices via immediate offsets:
    //   vA = +0, wA = +32, vB = +128, wB = +160 (uint4 units)
    const uint4* vw = (const uint4*)VWb + (size_t)i0s * 256 + (lane >> 5) * 64 + (lane & 31);

    uint4 vA = vw[0], wA = vw[32], vB = vw[128], wB = vw[160];
    vw += 256;
    float4 xq = *(const float4*)(xp + i0s);

    for (int ib = i0s; ib < i1s; ib += 4) {     // all segment lengths %4 == 0
        int xb = (ib + 4 < i1s) ? (ib + 4) : i0s;
        float4 xq_n = *(const float4*)(xp + xb);
        float xa[4] = {xq.x, xq.y, xq.z, xq.w};
        float pr[4];
#pragma unroll
        for (int j = 0; j < 4; ++j) {
            uint4 vAn = vw[0], wAn = vw[32], vBn = vw[128], wBn = vw[160];  // prefetch (padded past 784)
            vw += 256;
            v2f n, d;
            tree16(Aq, vA, wA, vB, wB, xa[j], n, d);
            float p = fmaf(n.x, __builtin_amdgcn_rcpf(d.x),
                           n.y * __builtin_amdgcn_rcpf(d.y));
            pr[j] = reduce64(p);
            vA = vAn; wA = wAn; vB = vBn; wB = wBn;
        }
        float4 b4 = *(const float4*)(bias + ib);
        if (lane == 63) {
            float4 o = make_float4(pr[0] + b4.x, pr[1] + b4.y, pr[2] + b4.z, pr[3] + b4.w);
            *(float4*)(out + (size_t)row * D_ + ib) = o;
        }
        xq = xq_n;
    }
}

extern "C" void kernel_launch(void* const* d_in, const int* in_sizes, int n_in,
                              void* d_out, int out_size, void* d_ws, size_t ws_size,
                              hipStream_t stream) {
    const float* px   = (const float*)d_in[0];  // [B, D]
    const float* W    = (const float*)d_in[1];  // [H, D]
    const float* c    = (const float*)d_in[2];  // [H]
    const float* V    = (const float*)d_in[3];  // [D, H]
    const float* bias = (const float*)d_in[4];  // [D]
    float* out = (float*)d_out;                 // [B, D]

    unsigned short* VWb = (unsigned short*)d_ws;              // 788*4*512 ushorts = 3.23 MB
    float* G    = (float*)((char*)d_ws + (size_t)788 * 4096); // [3][B][H]

    // 800 pack blocks + 3 ranges x 256 G-matmul blocks
    prep<<<dim3(1568), 256, 0, stream>>>(V, W, px, VWb, G);

    // 1024 blocks x 4 waves; block = (segment, 4 consecutive rows), wave = 1 row
    nade_main<<<dim3(1024), 256, 0, stream>>>(px, c, VWb, G, bias, out);
}